// Round 18
// baseline (262.881 us; speedup 1.0000x reference)
//
#include <hip/hip_runtime.h>
#include <hip/hip_bf16.h>
#include <hip/hip_fp16.h>

#define NN 8192
#define HIDD 128
#define NLAY 2

typedef __attribute__((ext_vector_type(8))) short bf16x8;
typedef __attribute__((ext_vector_type(4))) float f32x4;
typedef __attribute__((ext_vector_type(2))) float v2f;
typedef const void __attribute__((address_space(1)))* gas_ptr;
typedef void __attribute__((address_space(3)))* las_ptr;

static __device__ __forceinline__ unsigned short f2b(float x) {
    __hip_bfloat16 h = __float2bfloat16(x);
    return *reinterpret_cast<unsigned short*>(&h);
}
static __device__ __forceinline__ unsigned short f2h(float x) {
    __half h = __float2half(x);
    return *reinterpret_cast<unsigned short*>(&h);
}
static __device__ __forceinline__ float h2f(unsigned short u) {
    __half h = *reinterpret_cast<__half*>(&u);
    return __half2float(h);
}

static __device__ __forceinline__ unsigned long long spread4(unsigned long long x) {
    x = (x | (x << 24)) & 0x000000ff000000ffULL;
    x = (x | (x << 12)) & 0x000f000f000f000fULL;
    x = (x | (x << 6))  & 0x0303030303030303ULL;
    x = (x | (x << 3))  & 0x1111111111111111ULL;
    return x;
}

// ================================================================ pre-kernel
__global__ void k_pre(const int* __restrict__ adj, unsigned long long* __restrict__ bm,
                      const float* __restrict__ hin, const float* __restrict__ Wp,
                      const float* __restrict__ bp, float* __restrict__ hout,
                      const float* __restrict__ Wk, const float* __restrict__ Wq,
                      const float* __restrict__ a1, const float* __restrict__ a2,
                      const float* __restrict__ bk, const float* __restrict__ bq,
                      const float* __restrict__ Wm, const float* __restrict__ Wg,
                      unsigned short* __restrict__ BtP,
                      float* __restrict__ wka, float* __restrict__ wqa,
                      float* __restrict__ scal, float* __restrict__ lossacc) {
    __shared__ float ht[16][128];
    int b = blockIdx.x;
    int tid = threadIdx.x;
    if (b < 512) {
        int i0 = b * 16;
#pragma unroll
        for (int r = 0; r < 2; r++) {
            int q = r * 256 + tid;
            ((float4*)ht)[q] = ((const float4*)(hin + (size_t)i0 * 128))[q];
        }
        __syncthreads();
        int c = tid & 127, half = tid >> 7;
        float acc[8];
        float b0 = bp[c];
#pragma unroll
        for (int m = 0; m < 8; m++) acc[m] = b0;
        for (int k = 0; k < 128; k += 4) {
            float w0 = Wp[k * 128 + c], w1 = Wp[(k + 1) * 128 + c];
            float w2 = Wp[(k + 2) * 128 + c], w3 = Wp[(k + 3) * 128 + c];
#pragma unroll
            for (int m = 0; m < 8; m++) {
                float4 hv = *(const float4*)&ht[half + 2 * m][k];
                acc[m] = fmaf(hv.x, w0, acc[m]);
                acc[m] = fmaf(hv.y, w1, acc[m]);
                acc[m] = fmaf(hv.z, w2, acc[m]);
                acc[m] = fmaf(hv.w, w3, acc[m]);
            }
        }
#pragma unroll
        for (int m = 0; m < 8; m++) hout[(size_t)(i0 + half + 2 * m) * 128 + c] = acc[m];
    } else if (b < 514) {
        int l = b - 512;
        const float* a1L = a1 + l * 128;
        const float* a2L = a2 + l * 128;
        if (tid < 128) {
            const float* W1 = Wk + (size_t)l * 16384 + (size_t)tid * 128;
            const float* W2 = Wq + (size_t)l * 16384 + (size_t)tid * 128;
            float s1 = 0.f, s2 = 0.f;
            for (int c = 0; c < 128; c++) {
                s1 = fmaf(W1[c], a1L[c], s1);
                s2 = fmaf(W2[c], a2L[c], s2);
            }
            wka[l * 128 + tid] = s1;
            wqa[l * 128 + tid] = s2;
        } else if (tid == 128) {
            float s = 0.f;
            for (int c = 0; c < 128; c++) s = fmaf(bk[l * 128 + c], a1L[c], s);
            scal[l * 2 + 0] = s;
        } else if (tid == 129) {
            float s = 0.f;
            for (int c = 0; c < 128; c++) s = fmaf(bq[l * 128 + c], a2L[c], s);
            scal[l * 2 + 1] = s;
        } else if (tid == 130 && l == 0) {
            lossacc[0] = 0.f;
        }
    } else if (b < 520) {
        int l = (b - 514) / 3, kc = (b - 514) % 3;
        unsigned short* dst = BtP + (size_t)l * 49152 + (size_t)kc * 16384;
#pragma unroll
        for (int s8 = 0; s8 < 8; s8++) {
            int slot = s8 * 256 + tid;
            int col = slot >> 3;
            int g = (slot & 7) ^ (col & 7);
            int k0 = kc * 64 + g * 8;
            unsigned short o[8];
#pragma unroll
            for (int e = 0; e < 8; e++) {
                int k = k0 + e;
                float v;
                if (col < 128) v = (k < 128) ? Wm[(size_t)l * 16384 + k * 128 + col] : 0.f;
                else v = Wg[(size_t)l * 24576 + k * 128 + (col - 128)];
                o[e] = f2b(v);
            }
            *(int4*)&dst[slot * 8] = *(int4*)o;
        }
    } else {
        const long totalg = (long)NN * (NN / 256);
        int lane = tid & 63, w = tid >> 6;
        long nb = (long)gridDim.x - 520;
        long g = (long)(b - 520) * 4 + w;
        long ng = nb * 4;
        for (; g < totalg; g += ng) {
            int4 v = ((const int4*)adj)[g * 64 + lane];
            unsigned long long B0 = __ballot(v.x > 0);
            unsigned long long B1 = __ballot(v.y > 0);
            unsigned long long B2 = __ballot(v.z > 0);
            unsigned long long B3 = __ballot(v.w > 0);
            if (lane < 4) {
                int sh = lane * 16;
                unsigned long long W = spread4((B0 >> sh) & 0xFFFF)
                                     | (spread4((B1 >> sh) & 0xFFFF) << 1)
                                     | (spread4((B2 >> sh) & 0xFFFF) << 2)
                                     | (spread4((B3 >> sh) & 0xFFFF) << 3);
                bm[g * 4 + lane] = W;
            }
        }
    }
}

// ================================================================ gm v6 + merged btrans (l0 only)
__global__ void k_gm(const float* __restrict__ hbase, const unsigned short* __restrict__ aggs16,
                     int nslab, float* __restrict__ hstore, const float* __restrict__ zp,
                     const unsigned short* __restrict__ BtL,
                     const float* __restrict__ wka, const float* __restrict__ wqa,
                     const float* __restrict__ scal,
                     unsigned short* __restrict__ gmT, float* __restrict__ ek,
                     float* __restrict__ ek01, float* __restrict__ eq_,
                     float* __restrict__ eq01_, float* __restrict__ S,
                     unsigned* __restrict__ cnt, float* __restrict__ lossacc,
                     const unsigned* __restrict__ bm32, unsigned* __restrict__ bt32) {
    __shared__ __align__(16) unsigned short A_l[16 * 256];
    __shared__ __align__(16) unsigned short B_l[2048 * 8];   // 32KB; aliased by btrans branch
    __shared__ float htf[16][128];
    __shared__ float E[16][256];
    __shared__ unsigned short tb[128][24];
    __shared__ float redk[4][8], redq[4][8], redl[4];
    int tid = threadIdx.x;

    if (blockIdx.x >= NN / 16) {
        // ---- merged bitmask transpose (l0 only; 512 extra blocks)
        unsigned* t = (unsigned*)B_l;       // [64][65]
        int bb = blockIdx.x - NN / 16;
        int bi = bb >> 2, bj = bb & 3;
        int i0 = bi * 64, jw0 = bj * 64;
        int c = tid & 63, r4 = tid >> 6;
#pragma unroll
        for (int rr = 0; rr < 16; rr++) {
            int ir = rr * 4 + r4;
            t[ir * 65 + c] = bm32[(size_t)(i0 + ir) * 256 + jw0 + c];
        }
        __syncthreads();
#pragma unroll
        for (int rr = 0; rr < 16; rr++) {
            int jr = rr * 4 + r4;
            bt32[(size_t)(jw0 + jr) * NN + i0 + c] = t[c * 65 + jr];
        }
        return;
    }

    int i0 = blockIdx.x * 16;
    int lane = tid & 63, w = tid >> 6;

#define STAGE_B(kc)                                                                  \
    {                                                                                \
        _Pragma("unroll")                                                            \
        for (int r = 0; r < 8; r++) {                                                \
            int slot = r * 256 + tid;                                                \
            __builtin_amdgcn_global_load_lds(                                        \
                (gas_ptr)(BtL + (size_t)(kc) * 16384 + slot * 8),                    \
                (las_ptr)&B_l[slot * 8], 16, 0, 0);                                  \
        }                                                                            \
    }

    STAGE_B(0);

#pragma unroll
    for (int r = 0; r < 2; r++) {
        int q = r * 256 + tid;
        float4 hv = ((const float4*)(hbase + (size_t)i0 * 128))[q];
        if (nslab > 0) {
            float sx = 0.f, sy = 0.f, sz = 0.f, sw = 0.f;
            for (int s = 0; s < nslab; s++) {
                ushort4 a = ((const ushort4*)(aggs16 + (size_t)s * NN * HIDD))[(size_t)i0 * 32 + q];
                sx += h2f(a.x); sy += h2f(a.y); sz += h2f(a.z); sw += h2f(a.w);
            }
            hv.x = (hv.x + sx) * 0.5f;
            hv.y = (hv.y + sy) * 0.5f;
            hv.z = (hv.z + sz) * 0.5f;
            hv.w = (hv.w + sw) * 0.5f;
            ((float4*)(hstore + (size_t)i0 * 128))[q] = hv;
        }
        int row = q >> 5;
        int k = (q & 31) * 4;
        *(float4*)&htf[row][k] = hv;
        int ge = ((k >> 3) ^ (row & 7)) * 8 + (k & 7);
        unsigned p0, p1;
        asm("v_cvt_pk_bf16_f32 %0, %1, %2" : "=v"(p0) : "v"(hv.x), "v"(hv.y));
        asm("v_cvt_pk_bf16_f32 %0, %1, %2" : "=v"(p1) : "v"(hv.z), "v"(hv.w));
        *(unsigned*)&A_l[row * 256 + ge] = p0;
        *(unsigned*)&A_l[row * 256 + ge + 2] = p1;
    }
    {
        int q = tid;
        float4 zv = ((const float4*)(zp + (size_t)i0 * 64))[q];
        int row = q >> 4;
        int k = 128 + (q & 15) * 4;
        int ge = ((k >> 3) ^ (row & 7)) * 8 + (k & 7);
        unsigned p0, p1;
        asm("v_cvt_pk_bf16_f32 %0, %1, %2" : "=v"(p0) : "v"(zv.x), "v"(zv.y));
        asm("v_cvt_pk_bf16_f32 %0, %1, %2" : "=v"(p1) : "v"(zv.z), "v"(zv.w));
        *(unsigned*)&A_l[row * 256 + ge] = p0;
        *(unsigned*)&A_l[row * 256 + ge + 2] = p1;
    }
    __syncthreads();

    f32x4 acc[4];
#pragma unroll
    for (int ct = 0; ct < 4; ct++) acc[ct] = (f32x4){0.f, 0.f, 0.f, 0.f};
    int colbase = w * 64;
    int arow = lane & 15;

    for (int c = 0; c < 3; c++) {
        __builtin_amdgcn_s_setprio(1);
#pragma unroll
        for (int ks = 0; ks < 2; ks++) {
            int klocal = ks * 32 + (lane >> 4) * 8;
            int kb = c * 64 + klocal;
            bf16x8 av = *(const bf16x8*)&A_l[arow * 256 + (((kb >> 3) ^ (arow & 7)) * 8)];
            int gl = klocal >> 3;
#pragma unroll
            for (int ct = 0; ct < 4; ct++) {
                int col = colbase + ct * 16 + (lane & 15);
                bf16x8 bv = *(const bf16x8*)&B_l[col * 64 + ((gl ^ (col & 7)) * 8)];
                acc[ct] = __builtin_amdgcn_mfma_f32_16x16x32_bf16(av, bv, acc[ct], 0, 0, 0);
            }
        }
        __builtin_amdgcn_s_setprio(0);
        __syncthreads();
        if (c < 2) {
            STAGE_B(c + 1);
            __syncthreads();
        }
    }
#pragma unroll
    for (int ct = 0; ct < 4; ct++) {
        int col = colbase + ct * 16 + (lane & 15);
#pragma unroll
        for (int j = 0; j < 4; j++) {
            int row = (lane >> 4) * 4 + j;
            E[row][col] = acc[ct][j];
        }
    }
    __syncthreads();
    int c2 = tid & 127, half = tid >> 7;
    float lsum = 0.f;
    float gmv[8];
#pragma unroll
    for (int m = 0; m < 8; m++) {
        int row = half + 2 * m;
        float amv = E[row][c2];
        float agv = E[row][128 + c2];
        float gate = 1.f / (1.f + __expf(-agv));
        lsum += gate;
        gmv[m] = gate * fmaxf(amv, 0.f);
        tb[c2][row] = f2b(gmv[m]);
    }
    float wkac = wka[c2], wqac = wqa[c2];
    int wid = tid >> 6;
#pragma unroll
    for (int m = 0; m < 8; m++) {
        float vk = htf[half + 2 * m][c2] * wkac;
        float vq = gmv[m] * wqac;
#pragma unroll
        for (int o = 32; o; o >>= 1) {
            vk += __shfl_down(vk, o);
            vq += __shfl_down(vq, o);
        }
        if (lane == 0) { redk[wid][m] = vk; redq[wid][m] = vq; }
    }
#pragma unroll
    for (int o = 32; o; o >>= 1) lsum += __shfl_down(lsum, o);
    if (lane == 0) redl[wid] = lsum;
    __syncthreads();
    if (tid < 16) {
        int r = tid, hf = r & 1, m = r >> 1;
        const float LOG2E = 1.4426950408889634f;
        float kdl = (redk[2 * hf][m] + redk[2 * hf + 1][m] + scal[0]) * LOG2E;
        float ql = (redq[2 * hf][m] + redq[2 * hf + 1][m] + scal[1]) * LOG2E;
        ek[i0 + r] = exp2f(kdl);
        ek01[i0 + r] = exp2f(0.01f * kdl);
        eq_[i0 + r] = exp2f(ql);
        eq01_[i0 + r] = exp2f(0.01f * ql);
        S[i0 + r] = 0.f;
    } else if (tid == 16) {
        cnt[blockIdx.x] = 0;
    }
    if (tid == 0) atomicAdd(lossacc, redl[0] + redl[1] + redl[2] + redl[3]);
    int hh = tid >> 1, io = (tid & 1) * 8;
    *(int4*)&gmT[(size_t)hh * NN + i0 + io] = *(int4*)&tb[hh][io];
#undef STAGE_B
}

// ---------------------------------------------------------------- stats v5: pk 2-j/lane + eqc tail
__global__ void k_stats(const unsigned* __restrict__ bm32, const float* __restrict__ ek,
                        const float* __restrict__ ek01, const float* __restrict__ eq_,
                        const float* __restrict__ eq01_, float* __restrict__ S,
                        unsigned* __restrict__ cnt, float* __restrict__ eqc,
                        float* __restrict__ eq01c) {
    __shared__ __align__(16) float epa[2048];
    __shared__ __align__(16) float epb[2048];
    __shared__ int lastflag;
    int bid = blockIdx.x;
    int rs = bid >> 2, ch = bid & 3;
    int r0 = rs * 16;
    int base = ch * 2048;
    int tid = threadIdx.x, lane = tid & 63, w = tid >> 6;
#pragma unroll
    for (int p = 0; p < 2; p++) {
        int idx = p * 1024 + tid * 4;
        *(float4*)&epa[idx] = *(const float4*)(ek + base + idx);
        *(float4*)&epb[idx] = *(const float4*)(ek01 + base + idx);
    }
    float eqv[4], eq01v[4];
    unsigned mrow[4];
#pragma unroll
    for (int t = 0; t < 4; t++) {
        int row = r0 + w * 4 + t;
        eqv[t] = eq_[row];
        eq01v[t] = eq01_[row];
        mrow[t] = bm32[(size_t)row * 256 + ch * 64 + lane];
    }
    v2f s2[4];
#pragma unroll
    for (int t = 0; t < 4; t++) s2[t] = (v2f){0.f, 0.f};
    int sh0 = 31 - 2 * (lane & 15);
    __syncthreads();
#pragma unroll 2
    for (int jj = 0; jj < 16; jj++) {
        float2 ea2 = *(const float2*)&epa[jj * 128 + lane * 2];
        float2 eb2 = *(const float2*)&epb[jj * 128 + lane * 2];
        v2f ea = (v2f){ea2.x, ea2.y};
        v2f eb = (v2f){eb2.x, eb2.y};
        int widx = jj * 4 + (lane >> 4);
#pragma unroll
        for (int t = 0; t < 4; t++) {
            unsigned word = __shfl(mrow[t], widx);
            unsigned m0 = (unsigned)(((int)(word << sh0)) >> 31);
            unsigned m1 = (unsigned)(((int)(word << (sh0 - 1))) >> 31);
            union { v2f f; uint2 u; } V;
            V.f = __builtin_elementwise_max(ea * eqv[t], eb * eq01v[t]);
            V.u.x &= m0;
            V.u.y &= m1;
            s2[t] += V.f;
        }
    }
#pragma unroll
    for (int t = 0; t < 4; t++) {
        float v = s2[t].x + s2[t].y;
#pragma unroll
        for (int o = 32; o; o >>= 1) v += __shfl_xor(v, o);
        if (lane == 0) atomicAdd(&S[r0 + w * 4 + t], v);
    }
    __syncthreads();
    if (tid == 0) {
        __threadfence();
        unsigned old = atomicAdd(cnt + rs, 1u);
        lastflag = (old == 3u);
    }
    __syncthreads();
    if (lastflag && tid < 16) {
        int row = r0 + tid;
        float sv = atomicAdd(&S[row], 0.0f);   // device-coherent read
        float inv = (sv > 0.f) ? 1.0f / sv : 0.f;
        eqc[row] = eq_[row] * inv;
        eq01c[row] = eq01_[row] * inv;
    }
}

// ---------------------------------------------------------------- pass B
#define BJ 128
#define KC 64
#define NSPLIT 16
#define NCH ((NN / NSPLIT) / KC)

__launch_bounds__(256, 4)
__global__ void k_attn_gemm(const unsigned* __restrict__ bt32, const float* __restrict__ ek,
                            const float* __restrict__ ek01, const float* __restrict__ eqc,
                            const float* __restrict__ eq01c,
                            const unsigned short* __restrict__ gmT,
                            float* __restrict__ aggf, unsigned short* __restrict__ part16,
                            int use_atomic) {
    int id = blockIdx.x;
    int sp = id & 15;
    int jb = id >> 4;
    int j0 = jb * BJ;
    int ibase = sp * (NN / NSPLIT);
    int tid = threadIdx.x;
    int lane = tid & 63;
    int w = tid >> 6;
    int lo = lane & 15;
    int qw = lane >> 4;
    int shA = 31 - lo;
    int shB = 15 - lo;

    __shared__ __align__(16) unsigned short G_l[2][HIDD * KC];
    __shared__ __align__(16) unsigned mask_l[2][4 * KC];
    __shared__ __align__(16) float e_l[2][KC];
    __shared__ __align__(16) float e01_l[2][KC];

    float ekA   = ek  [j0 + w * 32 + lo];
    float ekA01 = ek01[j0 + w * 32 + lo];
    float ekB   = ek  [j0 + w * 32 + lo + 16];
    float ekB01 = ek01[j0 + w * 32 + lo + 16];
    v2f ekA2   = {ekA, ekA},     ekA012 = {ekA01, ekA01};
    v2f ekB2   = {ekB, ekB},     ekB012 = {ekB01, ekB01};

    int jq0 = j0 >> 5;
    unsigned mreg;
    float ereg, e01reg;
    int wbase = (tid & 192) * 8;

#define STAGE_G(buf, igx)                                                                   \
    {                                                                                       \
        _Pragma("unroll")                                                                   \
        for (int r = 0; r < 4; r++) {                                                       \
            int slot = r * 256 + tid;                                                       \
            int hh = slot >> 3, sd = slot & 7;                                              \
            const unsigned short* gsrc = gmT + (size_t)hh * NN + (igx) + ((sd ^ (hh & 7)) * 8); \
            __builtin_amdgcn_global_load_lds((gas_ptr)gsrc,                                 \
                (las_ptr)&G_l[buf][r * 2048 + wbase], 16, 0, 0);                            \
        }                                                                                   \
    }

    {
        int ig = ibase;
        STAGE_G(0, ig);
        mreg = bt32[(size_t)(jq0 + w) * NN + ig + lane];
        ereg = eqc[ig + lane];
        e01reg = eq01c[ig + lane];
        mask_l[0][tid] = mreg;
        if (tid < KC) { e_l[0][tid] = ereg; e01_l[0][tid] = e01reg; }
    }
    __syncthreads();

    f32x4 acc[2][8];
#pragma unroll
    for (int a = 0; a < 2; a++)
#pragma unroll
        for (int b = 0; b < 8; b++) acc[a][b] = (f32x4){0.f, 0.f, 0.f, 0.f};

    int cur = 0;
    for (int c = 0; c < NCH; c++) {
        if (c + 1 < NCH) {
            int ig = ibase + (c + 1) * KC;
            STAGE_G(cur ^ 1, ig);
            mreg = bt32[(size_t)(jq0 + w) * NN + ig + lane];
            ereg = eqc[ig + lane];
            e01reg = eq01c[ig + lane];
        }
#pragma unroll
        for (int kk = 0; kk < 2; kk++) {
            int kb = kk * 32 + qw * 8;
            uint4 ma = *(const uint4*)&mask_l[cur][w * 64 + kb];
            uint4 mb = *(const uint4*)&mask_l[cur][w * 64 + kb + 4];
            unsigned mw[8] = {ma.x, ma.y, ma.z, ma.w, mb.x, mb.y, mb.z, mb.w};
            union { unsigned u[4]; bf16x8 v; } A0, A1;
#pragma unroll
            for (int p = 0; p < 4; p++) {
                v2f e2 = *(const v2f*)&e_l[cur][kb + 2 * p];
                v2f f2 = *(const v2f*)&e01_l[cur][kb + 2 * p];
                v2f tA = __builtin_elementwise_max(ekA2 * e2, ekA012 * f2);
                v2f tB = __builtin_elementwise_max(ekB2 * e2, ekB012 * f2);
                unsigned wA, wB;
                asm("v_cvt_pk_bf16_f32 %0, %1, %2" : "=v"(wA) : "v"(tA.x), "v"(tA.y));
                asm("v_cvt_pk_bf16_f32 %0, %1, %2" : "=v"(wB) : "v"(tB.x), "v"(tB.y));
                unsigned m0 = mw[2 * p], m1 = mw[2 * p + 1];
                unsigned a0 = (unsigned)(((int)(m0 << shA)) >> 31);
                unsigned a1 = (unsigned)(((int)(m1 << shA)) >> 31);
                unsigned b0 = (unsigned)(((int)(m0 << shB)) >> 31);
                unsigned b1 = (unsigned)(((int)(m1 << shB)) >> 31);
                A0.u[p] = wA & ((a0 & 0xFFFFu) | (a1 & 0xFFFF0000u));
                A1.u[p] = wB & ((b0 & 0xFFFFu) | (b1 & 0xFFFF0000u));
            }
            __builtin_amdgcn_s_setprio(1);
#pragma unroll
            for (int hf = 0; hf < 8; hf++) {
                int hr = hf * 16 + lo;
                bf16x8 bv = *(const bf16x8*)&G_l[cur][hr * KC + ((kk * 32 + qw * 8) ^ ((hr & 7) << 3))];
                acc[0][hf] = __builtin_amdgcn_mfma_f32_16x16x32_bf16(A0.v, bv, acc[0][hf], 0, 0, 0);
                acc[1][hf] = __builtin_amdgcn_mfma_f32_16x16x32_bf16(A1.v, bv, acc[1][hf], 0, 0, 0);
            }
            __builtin_amdgcn_s_setprio(0);
        }
        if (c + 1 < NCH) {
            int nxt = cur ^ 1;
            mask_l[nxt][tid] = mreg;
            if (tid < KC) { e_l[nxt][tid] = ereg; e01_l[nxt][tid] = e01reg; }
        }
        __syncthreads();
        cur ^= 1;
    }
    int row_base = w * 32 + (lane >> 4) * 4;
    int col = lane & 15;
    size_t slab = (size_t)sp * NN * HIDD;
#pragma unroll
    for (int jf = 0; jf < 2; jf++)
#pragma unroll
        for (int hf = 0; hf < 8; hf++)
#pragma unroll
            for (int r = 0; r < 4; r++) {
                int j = j0 + row_base + jf * 16 + r;
                int hcol = hf * 16 + col;
                size_t off = (size_t)j * HIDD + hcol;
                if (use_atomic) atomicAdd(&aggf[off], acc[jf][hf][r]);
                else part16[slab + off] = f2h(acc[jf][hf][r]);
            }
#undef STAGE_G
}

// ---------------------------------------------------------------- final combine + loss
__global__ void k_combine(const unsigned short* __restrict__ acc16, const float* __restrict__ accf,
                          int nslab, int use_atomic,
                          const float* __restrict__ hin, float* __restrict__ hout,
                          const float* __restrict__ lossacc, float* __restrict__ lossout) {
    size_t i = (size_t)blockIdx.x * blockDim.x + threadIdx.x;
    float4 hv = ((const float4*)hin)[i];
    float sx = 0.f, sy = 0.f, sz = 0.f, sw = 0.f;
    if (use_atomic) {
        float4 a = ((const float4*)accf)[i];
        sx = a.x; sy = a.y; sz = a.z; sw = a.w;
    } else {
        for (int s = 0; s < nslab; s++) {
            ushort4 a = ((const ushort4*)(acc16 + (size_t)s * NN * HIDD))[i];
            sx += h2f(a.x); sy += h2f(a.y); sz += h2f(a.z); sw += h2f(a.w);
        }
    }
    float4 o;
    o.x = (sx + hv.x) * 0.5f;
    o.y = (sy + hv.y) * 0.5f;
    o.z = (sz + hv.z) * 0.5f;
    o.w = (sw + hv.w) * 0.5f;
    ((float4*)hout)[i] = o;
    if (lossout != nullptr && i == 0)
        lossout[0] = lossacc[0] * (1.0f / (float)((size_t)NN * HIDD * NLAY));
}

// ================================================================ host
extern "C" void kernel_launch(void* const* d_in, const int* in_sizes, int n_in,
                              void* d_out, int out_size, void* d_ws, size_t ws_size,
                              hipStream_t stream) {
    const float* h_in = (const float*)d_in[0];
    const int* adj = (const int*)d_in[1];
    const float* z = (const float*)d_in[2];
    const float* Wp = (const float*)d_in[3];
    const float* bp = (const float*)d_in[4];
    const float* Wm = (const float*)d_in[5];
    const float* bmv = (const float*)d_in[6];
    const float* Wg = (const float*)d_in[7];
    const float* bgv = (const float*)d_in[8];
    const float* Wk = (const float*)d_in[9];
    const float* bk = (const float*)d_in[10];
    const float* Wq = (const float*)d_in[11];
    const float* bq = (const float*)d_in[12];
    const float* a1 = (const float*)d_in[13];
    const float* a2 = (const float*)d_in[14];
    float* out = (float*)d_out;

    char* ws = (char*)d_ws;
    unsigned long long* BM64 = (unsigned long long*)(ws + 0);          // 8 MB
    unsigned* BM32 = (unsigned*)(ws + 0);
    unsigned* BT32 = (unsigned*)(ws + (8ull << 20));                   // 8 MB (transposed)
    float* hcur = (float*)(ws + (16ull << 20));                        // 4 MB
    unsigned short* gmT = (unsigned short*)(ws + (20ull << 20));       // 2 MB
    float* ek    = (float*)(ws + (22ull << 20));
    float* ek01  = (float*)(ws + (22ull << 20) + (32ull << 10));
    float* eq    = (float*)(ws + (22ull << 20) + (64ull << 10));
    float* eq01  = (float*)(ws + (22ull << 20) + (96ull << 10));
    float* S     = (float*)(ws + (22ull << 20) + (128ull << 10));
    float* wka   = (float*)(ws + (22ull << 20) + (160ull << 10));
    float* wqa   = (float*)(ws + (22ull << 20) + (164ull << 10));
    float* scal  = (float*)(ws + (22ull << 20) + (168ull << 10));
    float* lossacc = (float*)(ws + (22ull << 20) + (172ull << 10));
    unsigned* cnt = (unsigned*)(ws + (22ull << 20) + (173ull << 10)); // 2 KB
    unsigned short* BtP = (unsigned short*)(ws + (22ull << 20) + (176ull << 10)); // 192 KB
    float* eqc   = (float*)(ws + (22ull << 20) + (368ull << 10));     // 32 KB
    float* eq01c = (float*)(ws + (22ull << 20) + (400ull << 10));     // 32 KB
    float* agg = (float*)(ws + (23ull << 20));                         // 4 MB (atomic fallback)
    unsigned short* part16 = (unsigned short*)(ws + (27ull << 20));    // 16 x 2 MB
    int use_atomic = (ws_size < (60ull << 20)) ? 1 : 0;
    int nslab = use_atomic ? 1 : NSPLIT;

    k_pre<<<2048, 256, 0, stream>>>(adj, BM64, h_in, Wp, bp, hcur,
                                    Wk, Wq, a1, a2, bk, bq, Wm, Wg, BtP,
                                    wka, wqa, scal, lossacc);

    for (int l = 0; l < NLAY; l++) {
        int grid = NN / 16 + ((l == 0) ? 512 : 0);   // l0 carries merged btrans blocks
        k_gm<<<grid, 256, 0, stream>>>(
            hcur, part16, (l > 0 && !use_atomic) ? nslab : 0, hcur,
            z, BtP + (size_t)l * 49152,
            wka + l * 128, wqa + l * 128, scal + l * 2,
            gmT, ek, ek01, eq, eq01, S, cnt, lossacc, BM32, BT32);
        k_stats<<<(NN / 16) * 4, 256, 0, stream>>>(BM32, ek, ek01, eq, eq01, S, cnt, eqc, eq01c);
        if (use_atomic) hipMemsetAsync(agg, 0, (size_t)NN * HIDD * 4, stream);
        k_attn_gemm<<<(NN / BJ) * NSPLIT, 256, 0, stream>>>(BT32, ek, ek01, eqc, eq01c, gmT,
                                                            agg, part16, use_atomic);
        if (use_atomic && l == 0) {
            k_combine<<<NN * HIDD / 4 / 256, 256, 0, stream>>>(
                part16, agg, 1, 1, hcur, hcur, lossacc, (float*)nullptr);
        }
    }
    k_combine<<<NN * HIDD / 4 / 256, 256, 0, stream>>>(
        part16, agg, nslab, use_atomic, hcur, out, lossacc, out + (size_t)NN * HIDD);
}

// Round 19
// 227.247 us; speedup vs baseline: 1.1568x; 1.1568x over previous
//
#include <hip/hip_runtime.h>
#include <hip/hip_bf16.h>
#include <hip/hip_fp16.h>

#define NN 8192
#define HIDD 128
#define NLAY 2

typedef __attribute__((ext_vector_type(8))) short bf16x8;
typedef __attribute__((ext_vector_type(4))) float f32x4;
typedef __attribute__((ext_vector_type(2))) float v2f;
typedef const void __attribute__((address_space(1)))* gas_ptr;
typedef void __attribute__((address_space(3)))* las_ptr;

static __device__ __forceinline__ unsigned short f2b(float x) {
    __hip_bfloat16 h = __float2bfloat16(x);
    return *reinterpret_cast<unsigned short*>(&h);
}
static __device__ __forceinline__ unsigned short f2h(float x) {
    __half h = __float2half(x);
    return *reinterpret_cast<unsigned short*>(&h);
}
static __device__ __forceinline__ float h2f(unsigned short u) {
    __half h = *reinterpret_cast<__half*>(&u);
    return __half2float(h);
}

static __device__ __forceinline__ unsigned long long spread4(unsigned long long x) {
    x = (x | (x << 24)) & 0x000000ff000000ffULL;
    x = (x | (x << 12)) & 0x000f000f000f000fULL;
    x = (x | (x << 6))  & 0x0303030303030303ULL;
    x = (x | (x << 3))  & 0x1111111111111111ULL;
    return x;
}

// ================================================================ pre-kernel
__global__ void k_pre(const int* __restrict__ adj, unsigned long long* __restrict__ bm,
                      const float* __restrict__ hin, const float* __restrict__ Wp,
                      const float* __restrict__ bp, float* __restrict__ hout,
                      const float* __restrict__ Wk, const float* __restrict__ Wq,
                      const float* __restrict__ a1, const float* __restrict__ a2,
                      const float* __restrict__ bk, const float* __restrict__ bq,
                      const float* __restrict__ Wm, const float* __restrict__ Wg,
                      unsigned short* __restrict__ BtP,
                      float* __restrict__ wka, float* __restrict__ wqa,
                      float* __restrict__ scal, float* __restrict__ lossacc) {
    __shared__ float ht[16][128];
    int b = blockIdx.x;
    int tid = threadIdx.x;
    if (b < 512) {
        int i0 = b * 16;
#pragma unroll
        for (int r = 0; r < 2; r++) {
            int q = r * 256 + tid;
            ((float4*)ht)[q] = ((const float4*)(hin + (size_t)i0 * 128))[q];
        }
        __syncthreads();
        int c = tid & 127, half = tid >> 7;
        float acc[8];
        float b0 = bp[c];
#pragma unroll
        for (int m = 0; m < 8; m++) acc[m] = b0;
        for (int k = 0; k < 128; k += 4) {
            float w0 = Wp[k * 128 + c], w1 = Wp[(k + 1) * 128 + c];
            float w2 = Wp[(k + 2) * 128 + c], w3 = Wp[(k + 3) * 128 + c];
#pragma unroll
            for (int m = 0; m < 8; m++) {
                float4 hv = *(const float4*)&ht[half + 2 * m][k];
                acc[m] = fmaf(hv.x, w0, acc[m]);
                acc[m] = fmaf(hv.y, w1, acc[m]);
                acc[m] = fmaf(hv.z, w2, acc[m]);
                acc[m] = fmaf(hv.w, w3, acc[m]);
            }
        }
#pragma unroll
        for (int m = 0; m < 8; m++) hout[(size_t)(i0 + half + 2 * m) * 128 + c] = acc[m];
    } else if (b < 514) {
        int l = b - 512;
        const float* a1L = a1 + l * 128;
        const float* a2L = a2 + l * 128;
        if (tid < 128) {
            const float* W1 = Wk + (size_t)l * 16384 + (size_t)tid * 128;
            const float* W2 = Wq + (size_t)l * 16384 + (size_t)tid * 128;
            float s1 = 0.f, s2 = 0.f;
            for (int c = 0; c < 128; c++) {
                s1 = fmaf(W1[c], a1L[c], s1);
                s2 = fmaf(W2[c], a2L[c], s2);
            }
            wka[l * 128 + tid] = s1;
            wqa[l * 128 + tid] = s2;
        } else if (tid == 128) {
            float s = 0.f;
            for (int c = 0; c < 128; c++) s = fmaf(bk[l * 128 + c], a1L[c], s);
            scal[l * 2 + 0] = s;
        } else if (tid == 129) {
            float s = 0.f;
            for (int c = 0; c < 128; c++) s = fmaf(bq[l * 128 + c], a2L[c], s);
            scal[l * 2 + 1] = s;
        } else if (tid == 130 && l == 0) {
            lossacc[0] = 0.f;
        }
    } else if (b < 520) {
        int l = (b - 514) / 3, kc = (b - 514) % 3;
        unsigned short* dst = BtP + (size_t)l * 49152 + (size_t)kc * 16384;
#pragma unroll
        for (int s8 = 0; s8 < 8; s8++) {
            int slot = s8 * 256 + tid;
            int col = slot >> 3;
            int g = (slot & 7) ^ (col & 7);
            int k0 = kc * 64 + g * 8;
            unsigned short o[8];
#pragma unroll
            for (int e = 0; e < 8; e++) {
                int k = k0 + e;
                float v;
                if (col < 128) v = (k < 128) ? Wm[(size_t)l * 16384 + k * 128 + col] : 0.f;
                else v = Wg[(size_t)l * 24576 + k * 128 + (col - 128)];
                o[e] = f2b(v);
            }
            *(int4*)&dst[slot * 8] = *(int4*)o;
        }
    } else {
        const long totalg = (long)NN * (NN / 256);
        int lane = tid & 63, w = tid >> 6;
        long nb = (long)gridDim.x - 520;
        long g = (long)(b - 520) * 4 + w;
        long ng = nb * 4;
        for (; g < totalg; g += ng) {
            int4 v = ((const int4*)adj)[g * 64 + lane];
            unsigned long long B0 = __ballot(v.x > 0);
            unsigned long long B1 = __ballot(v.y > 0);
            unsigned long long B2 = __ballot(v.z > 0);
            unsigned long long B3 = __ballot(v.w > 0);
            if (lane < 4) {
                int sh = lane * 16;
                unsigned long long W = spread4((B0 >> sh) & 0xFFFF)
                                     | (spread4((B1 >> sh) & 0xFFFF) << 1)
                                     | (spread4((B2 >> sh) & 0xFFFF) << 2)
                                     | (spread4((B3 >> sh) & 0xFFFF) << 3);
                bm[g * 4 + lane] = W;
            }
        }
    }
}

// ================================================================ bitmask transpose
__global__ void k_btrans(const unsigned* __restrict__ bm32, unsigned* __restrict__ bt32) {
    __shared__ unsigned t[64][65];
    int bi = blockIdx.x >> 2;
    int bj = blockIdx.x & 3;
    int i0 = bi * 64, jw0 = bj * 64;
    int tid = threadIdx.x;
    int c = tid & 63, r4 = tid >> 6;
#pragma unroll
    for (int rr = 0; rr < 16; rr++) {
        int ir = rr * 4 + r4;
        t[ir][c] = bm32[(size_t)(i0 + ir) * 256 + jw0 + c];
    }
    __syncthreads();
#pragma unroll
    for (int rr = 0; rr < 16; rr++) {
        int jr = rr * 4 + r4;
        bt32[(size_t)(jw0 + jr) * NN + i0 + c] = t[c][jr];
    }
}

// ================================================================ gm v6: MFMA GEMM
__global__ void k_gm(const float* __restrict__ hbase, const unsigned short* __restrict__ aggs16,
                     int nslab, float* __restrict__ hstore, const float* __restrict__ zp,
                     const unsigned short* __restrict__ BtL,
                     const float* __restrict__ bmv, const float* __restrict__ bgv,
                     const float* __restrict__ wka, const float* __restrict__ wqa,
                     const float* __restrict__ scal,
                     unsigned short* __restrict__ gmT, float* __restrict__ ek,
                     float* __restrict__ ek01, float* __restrict__ eq_,
                     float* __restrict__ eq01_, float* __restrict__ S,
                     float* __restrict__ lossacc) {
    __shared__ __align__(16) unsigned short A_l[16 * 256];
    __shared__ __align__(16) unsigned short B_l[2048 * 8];
    __shared__ float htf[16][128];
    __shared__ float E[16][256];
    __shared__ unsigned short tb[128][24];
    __shared__ float redk[4][8], redq[4][8], redl[4];
    int i0 = blockIdx.x * 16;
    int tid = threadIdx.x;
    int lane = tid & 63, w = tid >> 6;

#define STAGE_B(kc)                                                                  \
    {                                                                                \
        _Pragma("unroll")                                                            \
        for (int r = 0; r < 8; r++) {                                                \
            int slot = r * 256 + tid;                                                \
            __builtin_amdgcn_global_load_lds(                                        \
                (gas_ptr)(BtL + (size_t)(kc) * 16384 + slot * 8),                    \
                (las_ptr)&B_l[slot * 8], 16, 0, 0);                                  \
        }                                                                            \
    }

    STAGE_B(0);

#pragma unroll
    for (int r = 0; r < 2; r++) {
        int q = r * 256 + tid;
        float4 hv = ((const float4*)(hbase + (size_t)i0 * 128))[q];
        if (nslab > 0) {
            float sx = 0.f, sy = 0.f, sz = 0.f, sw = 0.f;
            for (int s = 0; s < nslab; s++) {
                ushort4 a = ((const ushort4*)(aggs16 + (size_t)s * NN * HIDD))[(size_t)i0 * 32 + q];
                sx += h2f(a.x); sy += h2f(a.y); sz += h2f(a.z); sw += h2f(a.w);
            }
            hv.x = (hv.x + sx) * 0.5f;
            hv.y = (hv.y + sy) * 0.5f;
            hv.z = (hv.z + sz) * 0.5f;
            hv.w = (hv.w + sw) * 0.5f;
            ((float4*)(hstore + (size_t)i0 * 128))[q] = hv;
        }
        int row = q >> 5;
        int k = (q & 31) * 4;
        *(float4*)&htf[row][k] = hv;
        int ge = ((k >> 3) ^ (row & 7)) * 8 + (k & 7);
        unsigned p0, p1;
        asm("v_cvt_pk_bf16_f32 %0, %1, %2" : "=v"(p0) : "v"(hv.x), "v"(hv.y));
        asm("v_cvt_pk_bf16_f32 %0, %1, %2" : "=v"(p1) : "v"(hv.z), "v"(hv.w));
        *(unsigned*)&A_l[row * 256 + ge] = p0;
        *(unsigned*)&A_l[row * 256 + ge + 2] = p1;
    }
    {
        int q = tid;
        float4 zv = ((const float4*)(zp + (size_t)i0 * 64))[q];
        int row = q >> 4;
        int k = 128 + (q & 15) * 4;
        int ge = ((k >> 3) ^ (row & 7)) * 8 + (k & 7);
        unsigned p0, p1;
        asm("v_cvt_pk_bf16_f32 %0, %1, %2" : "=v"(p0) : "v"(zv.x), "v"(zv.y));
        asm("v_cvt_pk_bf16_f32 %0, %1, %2" : "=v"(p1) : "v"(zv.z), "v"(zv.w));
        *(unsigned*)&A_l[row * 256 + ge] = p0;
        *(unsigned*)&A_l[row * 256 + ge + 2] = p1;
    }
    __syncthreads();

    f32x4 acc[4];
#pragma unroll
    for (int ct = 0; ct < 4; ct++) acc[ct] = (f32x4){0.f, 0.f, 0.f, 0.f};
    int colbase = w * 64;
    int arow = lane & 15;

    for (int c = 0; c < 3; c++) {
        __builtin_amdgcn_s_setprio(1);
#pragma unroll
        for (int ks = 0; ks < 2; ks++) {
            int klocal = ks * 32 + (lane >> 4) * 8;
            int kb = c * 64 + klocal;
            bf16x8 av = *(const bf16x8*)&A_l[arow * 256 + (((kb >> 3) ^ (arow & 7)) * 8)];
            int gl = klocal >> 3;
#pragma unroll
            for (int ct = 0; ct < 4; ct++) {
                int col = colbase + ct * 16 + (lane & 15);
                bf16x8 bv = *(const bf16x8*)&B_l[col * 64 + ((gl ^ (col & 7)) * 8)];
                acc[ct] = __builtin_amdgcn_mfma_f32_16x16x32_bf16(av, bv, acc[ct], 0, 0, 0);
            }
        }
        __builtin_amdgcn_s_setprio(0);
        __syncthreads();
        if (c < 2) {
            STAGE_B(c + 1);
            __syncthreads();
        }
    }
#pragma unroll
    for (int ct = 0; ct < 4; ct++) {
        int col = colbase + ct * 16 + (lane & 15);
#pragma unroll
        for (int j = 0; j < 4; j++) {
            int row = (lane >> 4) * 4 + j;
            E[row][col] = acc[ct][j];
        }
    }
    __syncthreads();
    int c2 = tid & 127, half = tid >> 7;
    float lsum = 0.f;
    float gmv[8];
#pragma unroll
    for (int m = 0; m < 8; m++) {
        int row = half + 2 * m;
        float amv = E[row][c2];
        float agv = E[row][128 + c2];
        float gate = 1.f / (1.f + __expf(-agv));
        lsum += gate;
        gmv[m] = gate * fmaxf(amv, 0.f);
        tb[c2][row] = f2b(gmv[m]);
    }
    float wkac = wka[c2], wqac = wqa[c2];
    int wid = tid >> 6;
#pragma unroll
    for (int m = 0; m < 8; m++) {
        float vk = htf[half + 2 * m][c2] * wkac;
        float vq = gmv[m] * wqac;
#pragma unroll
        for (int o = 32; o; o >>= 1) {
            vk += __shfl_down(vk, o);
            vq += __shfl_down(vq, o);
        }
        if (lane == 0) { redk[wid][m] = vk; redq[wid][m] = vq; }
    }
#pragma unroll
    for (int o = 32; o; o >>= 1) lsum += __shfl_down(lsum, o);
    if (lane == 0) redl[wid] = lsum;
    __syncthreads();
    if (tid < 16) {
        int r = tid, hf = r & 1, m = r >> 1;
        const float LOG2E = 1.4426950408889634f;
        float kdl = (redk[2 * hf][m] + redk[2 * hf + 1][m] + scal[0]) * LOG2E;
        float ql = (redq[2 * hf][m] + redq[2 * hf + 1][m] + scal[1]) * LOG2E;
        ek[i0 + r] = exp2f(kdl);
        ek01[i0 + r] = exp2f(0.01f * kdl);
        eq_[i0 + r] = exp2f(ql);
        eq01_[i0 + r] = exp2f(0.01f * ql);
        S[i0 + r] = 0.f;
    }
    if (tid == 0) atomicAdd(lossacc, redl[0] + redl[1] + redl[2] + redl[3]);
    int hh = tid >> 1, io = (tid & 1) * 8;
    *(int4*)&gmT[(size_t)hh * NN + i0 + io] = *(int4*)&tb[hh][io];
#undef STAGE_B
}

// ---------------------------------------------------------------- stats v4: conflict-free split ep
__global__ void k_stats(const unsigned* __restrict__ bm32, const float* __restrict__ ek,
                        const float* __restrict__ ek01, const float* __restrict__ eq_,
                        const float* __restrict__ eq01_, float* __restrict__ S) {
    __shared__ __align__(16) float epa[2048];
    __shared__ __align__(16) float epb[2048];
    int bid = blockIdx.x;
    int rs = bid >> 2, ch = bid & 3;
    int r0 = rs * 16;
    int base = ch * 2048;
    int tid = threadIdx.x, lane = tid & 63, w = tid >> 6;
#pragma unroll
    for (int p = 0; p < 2; p++) {
        int idx = p * 1024 + tid * 4;
        *(float4*)&epa[idx] = *(const float4*)(ek + base + idx);
        *(float4*)&epb[idx] = *(const float4*)(ek01 + base + idx);
    }
    float eqv[4], eq01v[4];
    unsigned mrow[4];
#pragma unroll
    for (int t = 0; t < 4; t++) {
        int row = r0 + w * 4 + t;
        eqv[t] = eq_[row];
        eq01v[t] = eq01_[row];
        mrow[t] = bm32[(size_t)row * 256 + ch * 64 + lane];
    }
    float s[4] = {0.f, 0.f, 0.f, 0.f};
    __syncthreads();
#pragma unroll 4
    for (int jj = 0; jj < 32; jj++) {
        float ea = epa[jj * 64 + lane];
        float eb = epb[jj * 64 + lane];
        int widx = jj * 2 + (lane >> 5);
        int bit = lane & 31;
#pragma unroll
        for (int t = 0; t < 4; t++) {
            unsigned word = __shfl(mrow[t], widx);
            float v = fmaxf(ea * eqv[t], eb * eq01v[t]);
            s[t] += ((word >> bit) & 1) ? v : 0.f;
        }
    }
#pragma unroll
    for (int t = 0; t < 4; t++) {
        float v = s[t];
#pragma unroll
        for (int o = 32; o; o >>= 1) v += __shfl_xor(v, o);
        if (lane == 0) atomicAdd(&S[r0 + w * 4 + t], v);
    }
}

// ---------------------------------------------------------------- pass B
#define BJ 128
#define KC 64
#define NSPLIT 16
#define NCH ((NN / NSPLIT) / KC)

__launch_bounds__(256, 4)
__global__ void k_attn_gemm(const unsigned* __restrict__ bt32, const float* __restrict__ ek,
                            const float* __restrict__ ek01, const float* __restrict__ eq_,
                            const float* __restrict__ eq01_, const float* __restrict__ S,
                            const unsigned short* __restrict__ gmT,
                            float* __restrict__ aggf, unsigned short* __restrict__ part16,
                            int use_atomic) {
    int id = blockIdx.x;
    int sp = id & 15;
    int jb = id >> 4;
    int j0 = jb * BJ;
    int ibase = sp * (NN / NSPLIT);
    int tid = threadIdx.x;
    int lane = tid & 63;
    int w = tid >> 6;
    int lo = lane & 15;
    int qw = lane >> 4;
    int shA = 31 - lo;
    int shB = 15 - lo;

    __shared__ __align__(16) unsigned short G_l[2][HIDD * KC];
    __shared__ __align__(16) unsigned mask_l[2][4 * KC];
    __shared__ __align__(16) float e_l[2][KC];
    __shared__ __align__(16) float e01_l[2][KC];

    float ekA   = ek  [j0 + w * 32 + lo];
    float ekA01 = ek01[j0 + w * 32 + lo];
    float ekB   = ek  [j0 + w * 32 + lo + 16];
    float ekB01 = ek01[j0 + w * 32 + lo + 16];
    v2f ekA2   = {ekA, ekA},     ekA012 = {ekA01, ekA01};
    v2f ekB2   = {ekB, ekB},     ekB012 = {ekB01, ekB01};

    int jq0 = j0 >> 5;
    unsigned mreg;
    float ereg, e01reg, sreg;
    int wbase = (tid & 192) * 8;

#define STAGE_G(buf, igx)                                                                   \
    {                                                                                       \
        _Pragma("unroll")                                                                   \
        for (int r = 0; r < 4; r++) {                                                       \
            int slot = r * 256 + tid;                                                       \
            int hh = slot >> 3, sd = slot & 7;                                              \
            const unsigned short* gsrc = gmT + (size_t)hh * NN + (igx) + ((sd ^ (hh & 7)) * 8); \
            __builtin_amdgcn_global_load_lds((gas_ptr)gsrc,                                 \
                (las_ptr)&G_l[buf][r * 2048 + wbase], 16, 0, 0);                            \
        }                                                                                   \
    }

    {
        int ig = ibase;
        STAGE_G(0, ig);
        mreg = bt32[(size_t)(jq0 + w) * NN + ig + lane];
        ereg = eq_[ig + lane];
        e01reg = eq01_[ig + lane];
        sreg = S[ig + lane];
        mask_l[0][tid] = mreg;
        float inv = (sreg > 0.f) ? 1.0f / sreg : 0.f;
        if (tid < KC) { e_l[0][tid] = ereg * inv; e01_l[0][tid] = e01reg * inv; }
    }
    __syncthreads();

    f32x4 acc[2][8];
#pragma unroll
    for (int a = 0; a < 2; a++)
#pragma unroll
        for (int b = 0; b < 8; b++) acc[a][b] = (f32x4){0.f, 0.f, 0.f, 0.f};

    int cur = 0;
    for (int c = 0; c < NCH; c++) {
        if (c + 1 < NCH) {
            int ig = ibase + (c + 1) * KC;
            STAGE_G(cur ^ 1, ig);
            mreg = bt32[(size_t)(jq0 + w) * NN + ig + lane];
            ereg = eq_[ig + lane];
            e01reg = eq01_[ig + lane];
            sreg = S[ig + lane];
        }
#pragma unroll
        for (int kk = 0; kk < 2; kk++) {
            int kb = kk * 32 + qw * 8;
            uint4 ma = *(const uint4*)&mask_l[cur][w * 64 + kb];
            uint4 mb = *(const uint4*)&mask_l[cur][w * 64 + kb + 4];
            unsigned mw[8] = {ma.x, ma.y, ma.z, ma.w, mb.x, mb.y, mb.z, mb.w};
            union { unsigned u[4]; bf16x8 v; } A0, A1;
#pragma unroll
            for (int p = 0; p < 4; p++) {
                v2f e2 = *(const v2f*)&e_l[cur][kb + 2 * p];
                v2f f2 = *(const v2f*)&e01_l[cur][kb + 2 * p];
                v2f tA = __builtin_elementwise_max(ekA2 * e2, ekA012 * f2);
                v2f tB = __builtin_elementwise_max(ekB2 * e2, ekB012 * f2);
                unsigned wA, wB;
                asm("v_cvt_pk_bf16_f32 %0, %1, %2" : "=v"(wA) : "v"(tA.x), "v"(tA.y));
                asm("v_cvt_pk_bf16_f32 %0, %1, %2" : "=v"(wB) : "v"(tB.x), "v"(tB.y));
                unsigned m0 = mw[2 * p], m1 = mw[2 * p + 1];
                unsigned a0 = (unsigned)(((int)(m0 << shA)) >> 31);
                unsigned a1 = (unsigned)(((int)(m1 << shA)) >> 31);
                unsigned b0 = (unsigned)(((int)(m0 << shB)) >> 31);
                unsigned b1 = (unsigned)(((int)(m1 << shB)) >> 31);
                A0.u[p] = wA & ((a0 & 0xFFFFu) | (a1 & 0xFFFF0000u));
                A1.u[p] = wB & ((b0 & 0xFFFFu) | (b1 & 0xFFFF0000u));
            }
            __builtin_amdgcn_s_setprio(1);
#pragma unroll
            for (int hf = 0; hf < 8; hf++) {
                int hr = hf * 16 + lo;
                bf16x8 bv = *(const bf16x8*)&G_l[cur][hr * KC + ((kk * 32 + qw * 8) ^ ((hr & 7) << 3))];
                acc[0][hf] = __builtin_amdgcn_mfma_f32_16x16x32_bf16(A0.v, bv, acc[0][hf], 0, 0, 0);
                acc[1][hf] = __builtin_amdgcn_mfma_f32_16x16x32_bf16(A1.v, bv, acc[1][hf], 0, 0, 0);
            }
            __builtin_amdgcn_s_setprio(0);
        }
        if (c + 1 < NCH) {
            int nxt = cur ^ 1;
            mask_l[nxt][tid] = mreg;
            float inv = (sreg > 0.f) ? 1.0f / sreg : 0.f;
            if (tid < KC) { e_l[nxt][tid] = ereg * inv; e01_l[nxt][tid] = e01reg * inv; }
        }
        __syncthreads();
        cur ^= 1;
    }
    int row_base = w * 32 + (lane >> 4) * 4;
    int col = lane & 15;
    size_t slab = (size_t)sp * NN * HIDD;
#pragma unroll
    for (int jf = 0; jf < 2; jf++)
#pragma unroll
        for (int hf = 0; hf < 8; hf++)
#pragma unroll
            for (int r = 0; r < 4; r++) {
                int j = j0 + row_base + jf * 16 + r;
                int hcol = hf * 16 + col;
                size_t off = (size_t)j * HIDD + hcol;
                if (use_atomic) atomicAdd(&aggf[off], acc[jf][hf][r]);
                else part16[slab + off] = f2h(acc[jf][hf][r]);
            }
#undef STAGE_G
}

// ---------------------------------------------------------------- final combine + loss
__global__ void k_combine(const unsigned short* __restrict__ acc16, const float* __restrict__ accf,
                          int nslab, int use_atomic,
                          const float* __restrict__ hin, float* __restrict__ hout,
                          const float* __restrict__ lossacc, float* __restrict__ lossout) {
    size_t i = (size_t)blockIdx.x * blockDim.x + threadIdx.x;
    float4 hv = ((const float4*)hin)[i];
    float sx = 0.f, sy = 0.f, sz = 0.f, sw = 0.f;
    if (use_atomic) {
        float4 a = ((const float4*)accf)[i];
        sx = a.x; sy = a.y; sz = a.z; sw = a.w;
    } else {
        for (int s = 0; s < nslab; s++) {
            ushort4 a = ((const ushort4*)(acc16 + (size_t)s * NN * HIDD))[i];
            sx += h2f(a.x); sy += h2f(a.y); sz += h2f(a.z); sw += h2f(a.w);
        }
    }
    float4 o;
    o.x = (sx + hv.x) * 0.5f;
    o.y = (sy + hv.y) * 0.5f;
    o.z = (sz + hv.z) * 0.5f;
    o.w = (sw + hv.w) * 0.5f;
    ((float4*)hout)[i] = o;
    if (lossout != nullptr && i == 0)
        lossout[0] = lossacc[0] * (1.0f / (float)((size_t)NN * HIDD * NLAY));
}

// ================================================================ host
extern "C" void kernel_launch(void* const* d_in, const int* in_sizes, int n_in,
                              void* d_out, int out_size, void* d_ws, size_t ws_size,
                              hipStream_t stream) {
    const float* h_in = (const float*)d_in[0];
    const int* adj = (const int*)d_in[1];
    const float* z = (const float*)d_in[2];
    const float* Wp = (const float*)d_in[3];
    const float* bp = (const float*)d_in[4];
    const float* Wm = (const float*)d_in[5];
    const float* bmv = (const float*)d_in[6];
    const float* Wg = (const float*)d_in[7];
    const float* bgv = (const float*)d_in[8];
    const float* Wk = (const float*)d_in[9];
    const float* bk = (const float*)d_in[10];
    const float* Wq = (const float*)d_in[11];
    const float* bq = (const float*)d_in[12];
    const float* a1 = (const float*)d_in[13];
    const float* a2 = (const float*)d_in[14];
    float* out = (float*)d_out;

    char* ws = (char*)d_ws;
    unsigned long long* BM64 = (unsigned long long*)(ws + 0);          // 8 MB
    unsigned* BM32 = (unsigned*)(ws + 0);
    unsigned* BT32 = (unsigned*)(ws + (8ull << 20));                   // 8 MB (transposed)
    float* hcur = (float*)(ws + (16ull << 20));                        // 4 MB
    unsigned short* gmT = (unsigned short*)(ws + (20ull << 20));       // 2 MB
    float* ek    = (float*)(ws + (22ull << 20));
    float* ek01  = (float*)(ws + (22ull << 20) + (32ull << 10));
    float* eq    = (float*)(ws + (22ull << 20) + (64ull << 10));
    float* eq01  = (float*)(ws + (22ull << 20) + (96ull << 10));
    float* S     = (float*)(ws + (22ull << 20) + (128ull << 10));
    float* wka   = (float*)(ws + (22ull << 20) + (160ull << 10));
    float* wqa   = (float*)(ws + (22ull << 20) + (164ull << 10));
    float* scal  = (float*)(ws + (22ull << 20) + (168ull << 10));
    float* lossacc = (float*)(ws + (22ull << 20) + (172ull << 10));
    unsigned short* BtP = (unsigned short*)(ws + (22ull << 20) + (176ull << 10)); // 192 KB
    float* agg = (float*)(ws + (23ull << 20));                         // 4 MB (atomic fallback)
    unsigned short* part16 = (unsigned short*)(ws + (27ull << 20));    // 16 x 2 MB
    int use_atomic = (ws_size < (60ull << 20)) ? 1 : 0;
    int nslab = use_atomic ? 1 : NSPLIT;

    k_pre<<<2048, 256, 0, stream>>>(adj, BM64, h_in, Wp, bp, hcur,
                                    Wk, Wq, a1, a2, bk, bq, Wm, Wg, BtP,
                                    wka, wqa, scal, lossacc);
    k_btrans<<<512, 256, 0, stream>>>(BM32, BT32);

    for (int l = 0; l < NLAY; l++) {
        k_gm<<<NN / 16, 256, 0, stream>>>(
            hcur, part16, (l > 0 && !use_atomic) ? nslab : 0, hcur,
            z, BtP + (size_t)l * 49152, bmv + l * 128, bgv + l * 128,
            wka + l * 128, wqa + l * 128, scal + l * 2,
            gmT, ek, ek01, eq, eq01, S, lossacc);
        k_stats<<<(NN / 16) * 4, 256, 0, stream>>>(BM32, ek, ek01, eq, eq01, S);
        if (use_atomic) hipMemsetAsync(agg, 0, (size_t)NN * HIDD * 4, stream);
        k_attn_gemm<<<(NN / BJ) * NSPLIT, 256, 0, stream>>>(BT32, ek, ek01, eq, eq01, S, gmT,
                                                            agg, part16, use_atomic);
        if (use_atomic && l == 0) {
            k_combine<<<NN * HIDD / 4 / 256, 256, 0, stream>>>(
                part16, agg, 1, 1, hcur, hcur, lossacc, (float*)nullptr);
        }
    }
    k_combine<<<NN * HIDD / 4 / 256, 256, 0, stream>>>(
        part16, agg, nslab, use_atomic, hcur, out, lossacc, out + (size_t)NN * HIDD);
}

// Round 20
// 220.706 us; speedup vs baseline: 1.1911x; 1.0296x over previous
//
#include <hip/hip_runtime.h>
#include <hip/hip_bf16.h>
#include <hip/hip_fp16.h>

#define NN 8192
#define HIDD 128
#define NLAY 2

typedef __attribute__((ext_vector_type(8))) short bf16x8;
typedef __attribute__((ext_vector_type(4))) float f32x4;
typedef __attribute__((ext_vector_type(2))) float v2f;
typedef const void __attribute__((address_space(1)))* gas_ptr;
typedef void __attribute__((address_space(3)))* las_ptr;

static __device__ __forceinline__ unsigned short f2b(float x) {
    __hip_bfloat16 h = __float2bfloat16(x);
    return *reinterpret_cast<unsigned short*>(&h);
}
static __device__ __forceinline__ unsigned short f2h(float x) {
    __half h = __float2half(x);
    return *reinterpret_cast<unsigned short*>(&h);
}
static __device__ __forceinline__ float h2f(unsigned short u) {
    __half h = *reinterpret_cast<__half*>(&u);
    return __half2float(h);
}

static __device__ __forceinline__ unsigned long long spread4(unsigned long long x) {
    x = (x | (x << 24)) & 0x000000ff000000ffULL;
    x = (x | (x << 12)) & 0x000f000f000f000fULL;
    x = (x | (x << 6))  & 0x0303030303030303ULL;
    x = (x | (x << 3))  & 0x1111111111111111ULL;
    return x;
}

// ================================================================ pre-kernel
__global__ void k_pre(const int* __restrict__ adj, unsigned long long* __restrict__ bm,
                      const float* __restrict__ hin, const float* __restrict__ Wp,
                      const float* __restrict__ bp, float* __restrict__ hout,
                      const float* __restrict__ Wk, const float* __restrict__ Wq,
                      const float* __restrict__ a1, const float* __restrict__ a2,
                      const float* __restrict__ bk, const float* __restrict__ bq,
                      const float* __restrict__ Wm, const float* __restrict__ Wg,
                      unsigned short* __restrict__ BtP,
                      float* __restrict__ wka, float* __restrict__ wqa,
                      float* __restrict__ scal, float* __restrict__ lossacc) {
    __shared__ float ht[16][128];
    int b = blockIdx.x;
    int tid = threadIdx.x;
    if (b < 512) {
        int i0 = b * 16;
#pragma unroll
        for (int r = 0; r < 2; r++) {
            int q = r * 256 + tid;
            ((float4*)ht)[q] = ((const float4*)(hin + (size_t)i0 * 128))[q];
        }
        __syncthreads();
        int c = tid & 127, half = tid >> 7;
        float acc[8];
        float b0 = bp[c];
#pragma unroll
        for (int m = 0; m < 8; m++) acc[m] = b0;
        for (int k = 0; k < 128; k += 4) {
            float w0 = Wp[k * 128 + c], w1 = Wp[(k + 1) * 128 + c];
            float w2 = Wp[(k + 2) * 128 + c], w3 = Wp[(k + 3) * 128 + c];
#pragma unroll
            for (int m = 0; m < 8; m++) {
                float4 hv = *(const float4*)&ht[half + 2 * m][k];
                acc[m] = fmaf(hv.x, w0, acc[m]);
                acc[m] = fmaf(hv.y, w1, acc[m]);
                acc[m] = fmaf(hv.z, w2, acc[m]);
                acc[m] = fmaf(hv.w, w3, acc[m]);
            }
        }
#pragma unroll
        for (int m = 0; m < 8; m++) hout[(size_t)(i0 + half + 2 * m) * 128 + c] = acc[m];
    } else if (b < 514) {
        int l = b - 512;
        const float* a1L = a1 + l * 128;
        const float* a2L = a2 + l * 128;
        if (tid < 128) {
            const float* W1 = Wk + (size_t)l * 16384 + (size_t)tid * 128;
            const float* W2 = Wq + (size_t)l * 16384 + (size_t)tid * 128;
            float s1 = 0.f, s2 = 0.f;
            for (int c = 0; c < 128; c++) {
                s1 = fmaf(W1[c], a1L[c], s1);
                s2 = fmaf(W2[c], a2L[c], s2);
            }
            wka[l * 128 + tid] = s1;
            wqa[l * 128 + tid] = s2;
        } else if (tid == 128) {
            float s = 0.f;
            for (int c = 0; c < 128; c++) s = fmaf(bk[l * 128 + c], a1L[c], s);
            scal[l * 2 + 0] = s;
        } else if (tid == 129) {
            float s = 0.f;
            for (int c = 0; c < 128; c++) s = fmaf(bq[l * 128 + c], a2L[c], s);
            scal[l * 2 + 1] = s;
        } else if (tid == 130 && l == 0) {
            lossacc[0] = 0.f;
        }
    } else if (b < 520) {
        int l = (b - 514) / 3, kc = (b - 514) % 3;
        unsigned short* dst = BtP + (size_t)l * 49152 + (size_t)kc * 16384;
#pragma unroll
        for (int s8 = 0; s8 < 8; s8++) {
            int slot = s8 * 256 + tid;
            int col = slot >> 3;
            int g = (slot & 7) ^ (col & 7);
            int k0 = kc * 64 + g * 8;
            unsigned short o[8];
#pragma unroll
            for (int e = 0; e < 8; e++) {
                int k = k0 + e;
                float v;
                if (col < 128) v = (k < 128) ? Wm[(size_t)l * 16384 + k * 128 + col] : 0.f;
                else v = Wg[(size_t)l * 24576 + k * 128 + (col - 128)];
                o[e] = f2b(v);
            }
            *(int4*)&dst[slot * 8] = *(int4*)o;
        }
    } else {
        const long totalg = (long)NN * (NN / 256);
        int lane = tid & 63, w = tid >> 6;
        long nb = (long)gridDim.x - 520;
        long g = (long)(b - 520) * 4 + w;
        long ng = nb * 4;
        for (; g < totalg; g += ng) {
            int4 v = ((const int4*)adj)[g * 64 + lane];
            unsigned long long B0 = __ballot(v.x > 0);
            unsigned long long B1 = __ballot(v.y > 0);
            unsigned long long B2 = __ballot(v.z > 0);
            unsigned long long B3 = __ballot(v.w > 0);
            if (lane < 4) {
                int sh = lane * 16;
                unsigned long long W = spread4((B0 >> sh) & 0xFFFF)
                                     | (spread4((B1 >> sh) & 0xFFFF) << 1)
                                     | (spread4((B2 >> sh) & 0xFFFF) << 2)
                                     | (spread4((B3 >> sh) & 0xFFFF) << 3);
                bm[g * 4 + lane] = W;
            }
        }
    }
}

// ================================================================ bitmask transpose
__global__ void k_btrans(const unsigned* __restrict__ bm32, unsigned* __restrict__ bt32) {
    __shared__ unsigned t[64][65];
    int bi = blockIdx.x >> 2;
    int bj = blockIdx.x & 3;
    int i0 = bi * 64, jw0 = bj * 64;
    int tid = threadIdx.x;
    int c = tid & 63, r4 = tid >> 6;
#pragma unroll
    for (int rr = 0; rr < 16; rr++) {
        int ir = rr * 4 + r4;
        t[ir][c] = bm32[(size_t)(i0 + ir) * 256 + jw0 + c];
    }
    __syncthreads();
#pragma unroll
    for (int rr = 0; rr < 16; rr++) {
        int jr = rr * 4 + r4;
        bt32[(size_t)(jw0 + jr) * NN + i0 + c] = t[c][jr];
    }
}

// ================================================================ gm v6: MFMA GEMM
__global__ void k_gm(const float* __restrict__ hbase, const unsigned short* __restrict__ aggs16,
                     int nslab, float* __restrict__ hstore, const float* __restrict__ zp,
                     const unsigned short* __restrict__ BtL,
                     const float* __restrict__ bmv, const float* __restrict__ bgv,
                     const float* __restrict__ wka, const float* __restrict__ wqa,
                     const float* __restrict__ scal,
                     unsigned short* __restrict__ gmT, float* __restrict__ ek,
                     float* __restrict__ ek01, float* __restrict__ eq_,
                     float* __restrict__ eq01_, float* __restrict__ S,
                     float* __restrict__ lossacc) {
    __shared__ __align__(16) unsigned short A_l[16 * 256];
    __shared__ __align__(16) unsigned short B_l[2048 * 8];
    __shared__ float htf[16][128];
    __shared__ float E[16][256];
    __shared__ unsigned short tb[128][24];
    __shared__ float redk[4][8], redq[4][8], redl[4];
    int i0 = blockIdx.x * 16;
    int tid = threadIdx.x;
    int lane = tid & 63, w = tid >> 6;

#define STAGE_B(kc)                                                                  \
    {                                                                                \
        _Pragma("unroll")                                                            \
        for (int r = 0; r < 8; r++) {                                                \
            int slot = r * 256 + tid;                                                \
            __builtin_amdgcn_global_load_lds(                                        \
                (gas_ptr)(BtL + (size_t)(kc) * 16384 + slot * 8),                    \
                (las_ptr)&B_l[slot * 8], 16, 0, 0);                                  \
        }                                                                            \
    }

    STAGE_B(0);

#pragma unroll
    for (int r = 0; r < 2; r++) {
        int q = r * 256 + tid;
        float4 hv = ((const float4*)(hbase + (size_t)i0 * 128))[q];
        if (nslab > 0) {
            float sx = 0.f, sy = 0.f, sz = 0.f, sw = 0.f;
            for (int s = 0; s < nslab; s++) {
                ushort4 a = ((const ushort4*)(aggs16 + (size_t)s * NN * HIDD))[(size_t)i0 * 32 + q];
                sx += h2f(a.x); sy += h2f(a.y); sz += h2f(a.z); sw += h2f(a.w);
            }
            hv.x = (hv.x + sx) * 0.5f;
            hv.y = (hv.y + sy) * 0.5f;
            hv.z = (hv.z + sz) * 0.5f;
            hv.w = (hv.w + sw) * 0.5f;
            ((float4*)(hstore + (size_t)i0 * 128))[q] = hv;
        }
        int row = q >> 5;
        int k = (q & 31) * 4;
        *(float4*)&htf[row][k] = hv;
        int ge = ((k >> 3) ^ (row & 7)) * 8 + (k & 7);
        unsigned p0, p1;
        asm("v_cvt_pk_bf16_f32 %0, %1, %2" : "=v"(p0) : "v"(hv.x), "v"(hv.y));
        asm("v_cvt_pk_bf16_f32 %0, %1, %2" : "=v"(p1) : "v"(hv.z), "v"(hv.w));
        *(unsigned*)&A_l[row * 256 + ge] = p0;
        *(unsigned*)&A_l[row * 256 + ge + 2] = p1;
    }
    {
        int q = tid;
        float4 zv = ((const float4*)(zp + (size_t)i0 * 64))[q];
        int row = q >> 4;
        int k = 128 + (q & 15) * 4;
        int ge = ((k >> 3) ^ (row & 7)) * 8 + (k & 7);
        unsigned p0, p1;
        asm("v_cvt_pk_bf16_f32 %0, %1, %2" : "=v"(p0) : "v"(zv.x), "v"(zv.y));
        asm("v_cvt_pk_bf16_f32 %0, %1, %2" : "=v"(p1) : "v"(zv.z), "v"(zv.w));
        *(unsigned*)&A_l[row * 256 + ge] = p0;
        *(unsigned*)&A_l[row * 256 + ge + 2] = p1;
    }
    __syncthreads();

    f32x4 acc[4];
#pragma unroll
    for (int ct = 0; ct < 4; ct++) acc[ct] = (f32x4){0.f, 0.f, 0.f, 0.f};
    int colbase = w * 64;
    int arow = lane & 15;

    for (int c = 0; c < 3; c++) {
        __builtin_amdgcn_s_setprio(1);
#pragma unroll
        for (int ks = 0; ks < 2; ks++) {
            int klocal = ks * 32 + (lane >> 4) * 8;
            int kb = c * 64 + klocal;
            bf16x8 av = *(const bf16x8*)&A_l[arow * 256 + (((kb >> 3) ^ (arow & 7)) * 8)];
            int gl = klocal >> 3;
#pragma unroll
            for (int ct = 0; ct < 4; ct++) {
                int col = colbase + ct * 16 + (lane & 15);
                bf16x8 bv = *(const bf16x8*)&B_l[col * 64 + ((gl ^ (col & 7)) * 8)];
                acc[ct] = __builtin_amdgcn_mfma_f32_16x16x32_bf16(av, bv, acc[ct], 0, 0, 0);
            }
        }
        __builtin_amdgcn_s_setprio(0);
        __syncthreads();
        if (c < 2) {
            STAGE_B(c + 1);
            __syncthreads();
        }
    }
#pragma unroll
    for (int ct = 0; ct < 4; ct++) {
        int col = colbase + ct * 16 + (lane & 15);
#pragma unroll
        for (int j = 0; j < 4; j++) {
            int row = (lane >> 4) * 4 + j;
            E[row][col] = acc[ct][j];
        }
    }
    __syncthreads();
    int c2 = tid & 127, half = tid >> 7;
    float lsum = 0.f;
    float gmv[8];
#pragma unroll
    for (int m = 0; m < 8; m++) {
        int row = half + 2 * m;
        float amv = E[row][c2];
        float agv = E[row][128 + c2];
        float gate = 1.f / (1.f + __expf(-agv));
        lsum += gate;
        gmv[m] = gate * fmaxf(amv, 0.f);
        tb[c2][row] = f2b(gmv[m]);
    }
    float wkac = wka[c2], wqac = wqa[c2];
    int wid = tid >> 6;
#pragma unroll
    for (int m = 0; m < 8; m++) {
        float vk = htf[half + 2 * m][c2] * wkac;
        float vq = gmv[m] * wqac;
#pragma unroll
        for (int o = 32; o; o >>= 1) {
            vk += __shfl_down(vk, o);
            vq += __shfl_down(vq, o);
        }
        if (lane == 0) { redk[wid][m] = vk; redq[wid][m] = vq; }
    }
#pragma unroll
    for (int o = 32; o; o >>= 1) lsum += __shfl_down(lsum, o);
    if (lane == 0) redl[wid] = lsum;
    __syncthreads();
    if (tid < 16) {
        int r = tid, hf = r & 1, m = r >> 1;
        const float LOG2E = 1.4426950408889634f;
        float kdl = (redk[2 * hf][m] + redk[2 * hf + 1][m] + scal[0]) * LOG2E;
        float ql = (redq[2 * hf][m] + redq[2 * hf + 1][m] + scal[1]) * LOG2E;
        ek[i0 + r] = exp2f(kdl);
        ek01[i0 + r] = exp2f(0.01f * kdl);
        eq_[i0 + r] = exp2f(ql);
        eq01_[i0 + r] = exp2f(0.01f * ql);
        S[i0 + r] = 0.f;
    }
    if (tid == 0) atomicAdd(lossacc, redl[0] + redl[1] + redl[2] + redl[3]);
    int hh = tid >> 1, io = (tid & 1) * 8;
    *(int4*)&gmT[(size_t)hh * NN + i0 + io] = *(int4*)&tb[hh][io];
#undef STAGE_B
}

// ---------------------------------------------------------------- stats v5-pk (isolated): 2 j/lane, packed math
__global__ void k_stats(const unsigned* __restrict__ bm32, const float* __restrict__ ek,
                        const float* __restrict__ ek01, const float* __restrict__ eq_,
                        const float* __restrict__ eq01_, float* __restrict__ S) {
    __shared__ __align__(16) float epa[2048];
    __shared__ __align__(16) float epb[2048];
    int bid = blockIdx.x;
    int rs = bid >> 2, ch = bid & 3;
    int r0 = rs * 16;
    int base = ch * 2048;
    int tid = threadIdx.x, lane = tid & 63, w = tid >> 6;
#pragma unroll
    for (int p = 0; p < 2; p++) {
        int idx = p * 1024 + tid * 4;
        *(float4*)&epa[idx] = *(const float4*)(ek + base + idx);
        *(float4*)&epb[idx] = *(const float4*)(ek01 + base + idx);
    }
    float eqv[4], eq01v[4];
    unsigned mrow[4];
#pragma unroll
    for (int t = 0; t < 4; t++) {
        int row = r0 + w * 4 + t;
        eqv[t] = eq_[row];
        eq01v[t] = eq01_[row];
        mrow[t] = bm32[(size_t)row * 256 + ch * 64 + lane];
    }
    v2f s2[4];
#pragma unroll
    for (int t = 0; t < 4; t++) s2[t] = (v2f){0.f, 0.f};
    int sh0 = 31 - 2 * (lane & 15);   // bit 2*(lane&15) -> sign position
    __syncthreads();
#pragma unroll 2
    for (int jj = 0; jj < 16; jj++) {
        // lane handles j0 = jj*128 + lane*2, j1 = j0+1 (within this 2048-chunk)
        float2 ea2 = *(const float2*)&epa[jj * 128 + lane * 2];
        float2 eb2 = *(const float2*)&epb[jj * 128 + lane * 2];
        v2f ea = (v2f){ea2.x, ea2.y};
        v2f eb = (v2f){eb2.x, eb2.y};
        int widx = jj * 4 + (lane >> 4);   // word index j0>>5 within the 64 words
#pragma unroll
        for (int t = 0; t < 4; t++) {
            unsigned word = __shfl(mrow[t], widx);
            unsigned m0 = (unsigned)(((int)(word << sh0)) >> 31);
            unsigned m1 = (unsigned)(((int)(word << (sh0 - 1))) >> 31);
            union { v2f f; uint2 u; } V;
            V.f = __builtin_elementwise_max(ea * eqv[t], eb * eq01v[t]);
            V.u.x &= m0;
            V.u.y &= m1;
            s2[t] += V.f;
        }
    }
#pragma unroll
    for (int t = 0; t < 4; t++) {
        float v = s2[t].x + s2[t].y;
#pragma unroll
        for (int o = 32; o; o >>= 1) v += __shfl_xor(v, o);
        if (lane == 0) atomicAdd(&S[r0 + w * 4 + t], v);
    }
}

// ---------------------------------------------------------------- pass B
#define BJ 128
#define KC 64
#define NSPLIT 16
#define NCH ((NN / NSPLIT) / KC)

__launch_bounds__(256, 4)
__global__ void k_attn_gemm(const unsigned* __restrict__ bt32, const float* __restrict__ ek,
                            const float* __restrict__ ek01, const float* __restrict__ eq_,
                            const float* __restrict__ eq01_, const float* __restrict__ S,
                            const unsigned short* __restrict__ gmT,
                            float* __restrict__ aggf, unsigned short* __restrict__ part16,
                            int use_atomic) {
    int id = blockIdx.x;
    int sp = id & 15;
    int jb = id >> 4;
    int j0 = jb * BJ;
    int ibase = sp * (NN / NSPLIT);
    int tid = threadIdx.x;
    int lane = tid & 63;
    int w = tid >> 6;
    int lo = lane & 15;
    int qw = lane >> 4;
    int shA = 31 - lo;
    int shB = 15 - lo;

    __shared__ __align__(16) unsigned short G_l[2][HIDD * KC];
    __shared__ __align__(16) unsigned mask_l[2][4 * KC];
    __shared__ __align__(16) float e_l[2][KC];
    __shared__ __align__(16) float e01_l[2][KC];

    float ekA   = ek  [j0 + w * 32 + lo];
    float ekA01 = ek01[j0 + w * 32 + lo];
    float ekB   = ek  [j0 + w * 32 + lo + 16];
    float ekB01 = ek01[j0 + w * 32 + lo + 16];
    v2f ekA2   = {ekA, ekA},     ekA012 = {ekA01, ekA01};
    v2f ekB2   = {ekB, ekB},     ekB012 = {ekB01, ekB01};

    int jq0 = j0 >> 5;
    unsigned mreg;
    float ereg, e01reg, sreg;
    int wbase = (tid & 192) * 8;

#define STAGE_G(buf, igx)                                                                   \
    {                                                                                       \
        _Pragma("unroll")                                                                   \
        for (int r = 0; r < 4; r++) {                                                       \
            int slot = r * 256 + tid;                                                       \
            int hh = slot >> 3, sd = slot & 7;                                              \
            const unsigned short* gsrc = gmT + (size_t)hh * NN + (igx) + ((sd ^ (hh & 7)) * 8); \
            __builtin_amdgcn_global_load_lds((gas_ptr)gsrc,                                 \
                (las_ptr)&G_l[buf][r * 2048 + wbase], 16, 0, 0);                            \
        }                                                                                   \
    }

    {
        int ig = ibase;
        STAGE_G(0, ig);
        mreg = bt32[(size_t)(jq0 + w) * NN + ig + lane];
        ereg = eq_[ig + lane];
        e01reg = eq01_[ig + lane];
        sreg = S[ig + lane];
        mask_l[0][tid] = mreg;
        float inv = (sreg > 0.f) ? 1.0f / sreg : 0.f;
        if (tid < KC) { e_l[0][tid] = ereg * inv; e01_l[0][tid] = e01reg * inv; }
    }
    __syncthreads();

    f32x4 acc[2][8];
#pragma unroll
    for (int a = 0; a < 2; a++)
#pragma unroll
        for (int b = 0; b < 8; b++) acc[a][b] = (f32x4){0.f, 0.f, 0.f, 0.f};

    int cur = 0;
    for (int c = 0; c < NCH; c++) {
        if (c + 1 < NCH) {
            int ig = ibase + (c + 1) * KC;
            STAGE_G(cur ^ 1, ig);
            mreg = bt32[(size_t)(jq0 + w) * NN + ig + lane];
            ereg = eq_[ig + lane];
            e01reg = eq01_[ig + lane];
            sreg = S[ig + lane];
        }
#pragma unroll
        for (int kk = 0; kk < 2; kk++) {
            int kb = kk * 32 + qw * 8;
            uint4 ma = *(const uint4*)&mask_l[cur][w * 64 + kb];
            uint4 mb = *(const uint4*)&mask_l[cur][w * 64 + kb + 4];
            unsigned mw[8] = {ma.x, ma.y, ma.z, ma.w, mb.x, mb.y, mb.z, mb.w};
            union { unsigned u[4]; bf16x8 v; } A0, A1;
#pragma unroll
            for (int p = 0; p < 4; p++) {
                v2f e2 = *(const v2f*)&e_l[cur][kb + 2 * p];
                v2f f2 = *(const v2f*)&e01_l[cur][kb + 2 * p];
                v2f tA = __builtin_elementwise_max(ekA2 * e2, ekA012 * f2);
                v2f tB = __builtin_elementwise_max(ekB2 * e2, ekB012 * f2);
                unsigned wA, wB;
                asm("v_cvt_pk_bf16_f32 %0, %1, %2" : "=v"(wA) : "v"(tA.x), "v"(tA.y));
                asm("v_cvt_pk_bf16_f32 %0, %1, %2" : "=v"(wB) : "v"(tB.x), "v"(tB.y));
                unsigned m0 = mw[2 * p], m1 = mw[2 * p + 1];
                unsigned a0 = (unsigned)(((int)(m0 << shA)) >> 31);
                unsigned a1 = (unsigned)(((int)(m1 << shA)) >> 31);
                unsigned b0 = (unsigned)(((int)(m0 << shB)) >> 31);
                unsigned b1 = (unsigned)(((int)(m1 << shB)) >> 31);
                A0.u[p] = wA & ((a0 & 0xFFFFu) | (a1 & 0xFFFF0000u));
                A1.u[p] = wB & ((b0 & 0xFFFFu) | (b1 & 0xFFFF0000u));
            }
            __builtin_amdgcn_s_setprio(1);
#pragma unroll
            for (int hf = 0; hf < 8; hf++) {
                int hr = hf * 16 + lo;
                bf16x8 bv = *(const bf16x8*)&G_l[cur][hr * KC + ((kk * 32 + qw * 8) ^ ((hr & 7) << 3))];
                acc[0][hf] = __builtin_amdgcn_mfma_f32_16x16x32_bf16(A0.v, bv, acc[0][hf], 0, 0, 0);
                acc[1][hf] = __builtin_amdgcn_mfma_f32_16x16x32_bf16(A1.v, bv, acc[1][hf], 0, 0, 0);
            }
            __builtin_amdgcn_s_setprio(0);
        }
        if (c + 1 < NCH) {
            int nxt = cur ^ 1;
            mask_l[nxt][tid] = mreg;
            float inv = (sreg > 0.f) ? 1.0f / sreg : 0.f;
            if (tid < KC) { e_l[nxt][tid] = ereg * inv; e01_l[nxt][tid] = e01reg * inv; }
        }
        __syncthreads();
        cur ^= 1;
    }
    int row_base = w * 32 + (lane >> 4) * 4;
    int col = lane & 15;
    size_t slab = (size_t)sp * NN * HIDD;
#pragma unroll
    for (int jf = 0; jf < 2; jf++)
#pragma unroll
        for (int hf = 0; hf < 8; hf++)
#pragma unroll
            for (int r = 0; r < 4; r++) {
                int j = j0 + row_base + jf * 16 + r;
                int hcol = hf * 16 + col;
                size_t off = (size_t)j * HIDD + hcol;
                if (use_atomic) atomicAdd(&aggf[off], acc[jf][hf][r]);
                else part16[slab + off] = f2h(acc[jf][hf][r]);
            }
#undef STAGE_G
}

// ---------------------------------------------------------------- final combine + loss
__global__ void k_combine(const unsigned short* __restrict__ acc16, const float* __restrict__ accf,
                          int nslab, int use_atomic,
                          const float* __restrict__ hin, float* __restrict__ hout,
                          const float* __restrict__ lossacc, float* __restrict__ lossout) {
    size_t i = (size_t)blockIdx.x * blockDim.x + threadIdx.x;
    float4 hv = ((const float4*)hin)[i];
    float sx = 0.f, sy = 0.f, sz = 0.f, sw = 0.f;
    if (use_atomic) {
        float4 a = ((const float4*)accf)[i];
        sx = a.x; sy = a.y; sz = a.z; sw = a.w;
    } else {
        for (int s = 0; s < nslab; s++) {
            ushort4 a = ((const ushort4*)(acc16 + (size_t)s * NN * HIDD))[i];
            sx += h2f(a.x); sy += h2f(a.y); sz += h2f(a.z); sw += h2f(a.w);
        }
    }
    float4 o;
    o.x = (sx + hv.x) * 0.5f;
    o.y = (sy + hv.y) * 0.5f;
    o.z = (sz + hv.z) * 0.5f;
    o.w = (sw + hv.w) * 0.5f;
    ((float4*)hout)[i] = o;
    if (lossout != nullptr && i == 0)
        lossout[0] = lossacc[0] * (1.0f / (float)((size_t)NN * HIDD * NLAY));
}

// ================================================================ host
extern "C" void kernel_launch(void* const* d_in, const int* in_sizes, int n_in,
                              void* d_out, int out_size, void* d_ws, size_t ws_size,
                              hipStream_t stream) {
    const float* h_in = (const float*)d_in[0];
    const int* adj = (const int*)d_in[1];
    const float* z = (const float*)d_in[2];
    const float* Wp = (const float*)d_in[3];
    const float* bp = (const float*)d_in[4];
    const float* Wm = (const float*)d_in[5];
    const float* bmv = (const float*)d_in[6];
    const float* Wg = (const float*)d_in[7];
    const float* bgv = (const float*)d_in[8];
    const float* Wk = (const float*)d_in[9];
    const float* bk = (const float*)d_in[10];
    const float* Wq = (const float*)d_in[11];
    const float* bq = (const float*)d_in[12];
    const float* a1 = (const float*)d_in[13];
    const float* a2 = (const float*)d_in[14];
    float* out = (float*)d_out;

    char* ws = (char*)d_ws;
    unsigned long long* BM64 = (unsigned long long*)(ws + 0);          // 8 MB
    unsigned* BM32 = (unsigned*)(ws + 0);
    unsigned* BT32 = (unsigned*)(ws + (8ull << 20));                   // 8 MB (transposed)
    float* hcur = (float*)(ws + (16ull << 20));                        // 4 MB
    unsigned short* gmT = (unsigned short*)(ws + (20ull << 20));       // 2 MB
    float* ek    = (float*)(ws + (22ull << 20));
    float* ek01  = (float*)(ws + (22ull << 20) + (32ull << 10));
    float* eq    = (float*)(ws + (22ull << 20) + (64ull << 10));
    float* eq01  = (float*)(ws + (22ull << 20) + (96ull << 10));
    float* S     = (float*)(ws + (22ull << 20) + (128ull << 10));
    float* wka   = (float*)(ws + (22ull << 20) + (160ull << 10));
    float* wqa   = (float*)(ws + (22ull << 20) + (164ull << 10));
    float* scal  = (float*)(ws + (22ull << 20) + (168ull << 10));
    float* lossacc = (float*)(ws + (22ull << 20) + (172ull << 10));
    unsigned short* BtP = (unsigned short*)(ws + (22ull << 20) + (176ull << 10)); // 192 KB
    float* agg = (float*)(ws + (23ull << 20));                         // 4 MB (atomic fallback)
    unsigned short* part16 = (unsigned short*)(ws + (27ull << 20));    // 16 x 2 MB
    int use_atomic = (ws_size < (60ull << 20)) ? 1 : 0;
    int nslab = use_atomic ? 1 : NSPLIT;

    k_pre<<<2048, 256, 0, stream>>>(adj, BM64, h_in, Wp, bp, hcur,
                                    Wk, Wq, a1, a2, bk, bq, Wm, Wg, BtP,
                                    wka, wqa, scal, lossacc);
    k_btrans<<<512, 256, 0, stream>>>(BM32, BT32);

    for (int l = 0; l < NLAY; l++) {
        k_gm<<<NN / 16, 256, 0, stream>>>(
            hcur, part16, (l > 0 && !use_atomic) ? nslab : 0, hcur,
            z, BtP + (size_t)l * 49152, bmv + l * 128, bgv + l * 128,
            wka + l * 128, wqa + l * 128, scal + l * 2,
            gmT, ek, ek01, eq, eq01, S, lossacc);
        k_stats<<<(NN / 16) * 4, 256, 0, stream>>>(BM32, ek, ek01, eq, eq01, S);
        if (use_atomic) hipMemsetAsync(agg, 0, (size_t)NN * HIDD * 4, stream);
        k_attn_gemm<<<(NN / BJ) * NSPLIT, 256, 0, stream>>>(BT32, ek, ek01, eq, eq01, S, gmT,
                                                            agg, part16, use_atomic);
        if (use_atomic && l == 0) {
            k_combine<<<NN * HIDD / 4 / 256, 256, 0, stream>>>(
                part16, agg, 1, 1, hcur, hcur, lossacc, (float*)nullptr);
        }
    }
    k_combine<<<NN * HIDD / 4 / 256, 256, 0, stream>>>(
        part16, agg, nslab, use_atomic, hcur, out, lossacc, out + (size_t)NN * HIDD);
}